// Round 4
// baseline (8833.367 us; speedup 1.0000x reference)
//
#include <hip/hip_runtime.h>

// Problem constants
#define NB 512   // batch
#define NT 512   // time
#define NI 128   // input dim
#define NH 256   // hidden dim
#define NG 1024  // 4*NH gate rows
#define NKT 12   // K tiles of 32 (K = 384 = NI + NH)
#define GS 16    // sequences per group (= MFMA N)
#define NGRP 32  // groups
#define EPSV 1e-5f

typedef __attribute__((ext_vector_type(8))) short bf16x8;
typedef __attribute__((ext_vector_type(4))) float f32x4;

__device__ __forceinline__ unsigned short f32_to_bf16(float f) {
  unsigned int u = __float_as_uint(f);
  u += 0x7fffu + ((u >> 16) & 1u);   // RNE
  return (unsigned short)(u >> 16);
}

// ---------------------------------------------------------------------------
// Prep: swizzle fused weights into A-fragment order.
// Wsw element ((rt*12 + kt)*64 + lane)*8 + i  =  W[g][k],
//   g = rt*16 + (lane&15),  k = kt*32 + (lane>>4)*8 + i
// so a wave's global_load_dwordx4 at (rt,kt) IS its mfma A-fragment.
// Also bsum = b_ih + b_hh.
// ---------------------------------------------------------------------------
__global__ void prep_kernel(const float* __restrict__ W_ih, const float* __restrict__ W_hh,
                            const float* __restrict__ b_ih, const float* __restrict__ b_hh,
                            unsigned short* __restrict__ Wsw, float* __restrict__ bsum) {
  int idx = blockIdx.x * blockDim.x + threadIdx.x;   // 64*12*512 = 393216
  if (idx < 64 * NKT * 512) {
    int rt  = idx / (NKT * 512);
    int rem = idx - rt * (NKT * 512);
    int kt  = rem >> 9;
    int l2  = rem & 511;
    int lane = l2 >> 3, i = l2 & 7;
    int g = rt * 16 + (lane & 15);
    int k = kt * 32 + (lane >> 4) * 8 + i;
    float w = (k < NI) ? W_ih[g * NI + k] : W_hh[g * NH + (k - NI)];
    Wsw[idx] = f32_to_bf16(w);
  }
  if (idx < NG) bsum[idx] = b_ih[idx] + b_hh[idx];
}

// ---------------------------------------------------------------------------
// Rank-sort by length (descending) -> perm
// ---------------------------------------------------------------------------
__global__ void sort_kernel(const int* __restrict__ lengths, int* __restrict__ perm) {
  int i = threadIdx.x;
  __shared__ int L[NB];
  int li = lengths[i];
  L[i] = li;
  __syncthreads();
  int r = 0;
  for (int k = 0; k < NB; ++k) {
    int lk = L[k];
    r += (lk > li) || (lk == li && k < i);
  }
  perm[r] = i;
}

// ---------------------------------------------------------------------------
// Main: 32 blocks x 1024 threads. Block = 16 sorted sequences.
// Per step: gates(1024x16) = Wsw(1024x384) * xh(384x16) via mfma_16x16x32_bf16.
// Wave w owns D row-tiles {w, 16+w, 32+w, 48+w} = all 4 gates of units
// [16w, 16w+16) -> cell update is wave-local in registers.
// xh (bf16, B-frag layout) in LDS: k-tiles 0..3 = x_t, 4..11 = h.
// ---------------------------------------------------------------------------
__global__ __launch_bounds__(1024, 4)
void lstm_ln_kernel(const float* __restrict__ X, const int* __restrict__ lengths,
                    const int* __restrict__ perm, const unsigned short* __restrict__ Wsw,
                    const float* __restrict__ bsum, const float* __restrict__ gamma,
                    const float* __restrict__ beta, float* __restrict__ out) {
  __shared__ unsigned short xh[NKT * 512];   // 12 KB, B-fragment order
  __shared__ float hf[GS * 260];             // final h, padded stride (bank spread)
  __shared__ int sseq[GS], slen[GS];

  const int tid  = threadIdx.x;
  const int w    = tid >> 6;     // wave 0..15
  const int lane = tid & 63;
  const int bcol = lane & 15;    // sequence column
  const int quad = lane >> 4;

  if (tid < GS) {
    int sid = perm[blockIdx.x * GS + tid];
    sseq[tid] = sid;
    slen[tid] = lengths[sid];
  }
  for (int v = tid; v < NKT * 512; v += 1024) xh[v] = 0;   // h starts at 0
  __syncthreads();

  const int lmax = slen[0];        // sorted desc -> first is group max
  const int lenb = slen[bcol];

  // --- x staging: 2048 bf16 values/step, 2 per thread, addresses step-invariant
  const int v0 = tid, v1 = tid + 1024;
  const int b0 = v0 >> 7, k0 = v0 & 127;
  const int b1 = v1 >> 7, k1 = v1 & 127;
  const float* __restrict__ xp0 = X + (size_t)sseq[b0] * NT * NI + k0;
  const float* __restrict__ xp1 = X + (size_t)sseq[b1] * NT * NI + k1;
  const int xd0 = (k0 >> 5) * 512 + (((k0 & 31) >> 3) * 16 + b0) * 8 + (k0 & 7);
  const int xd1 = (k1 >> 5) * 512 + (((k1 & 31) >> 3) * 16 + b1) * 8 + (k1 & 7);

  // --- A-fragment pointers: rt = rtl*16 + w ; frag kt at ptr + kt*64
  const bf16x8* __restrict__ Ap0 = (const bf16x8*)Wsw + (size_t)((0 * 16 + w) * NKT) * 64 + lane;
  const bf16x8* __restrict__ Ap1 = (const bf16x8*)Wsw + (size_t)((1 * 16 + w) * NKT) * 64 + lane;
  const bf16x8* __restrict__ Ap2 = (const bf16x8*)Wsw + (size_t)((2 * 16 + w) * NKT) * 64 + lane;
  const bf16x8* __restrict__ Ap3 = (const bf16x8*)Wsw + (size_t)((3 * 16 + w) * NKT) * 64 + lane;

  // --- bias fragments (D row = quad*4 + r within tile)
  const int grow = w * 16 + quad * 4;
  const f32x4 bsf0 = *(const f32x4*)(bsum + 0 * 256 + grow);
  const f32x4 bsf1 = *(const f32x4*)(bsum + 1 * 256 + grow);
  const f32x4 bsf2 = *(const f32x4*)(bsum + 2 * 256 + grow);
  const f32x4 bsf3 = *(const f32x4*)(bsum + 3 * 256 + grow);

  // --- h write-back LDS indices (unit j = grow + r, k = 128 + j)
  int hidx[4];
#pragma unroll
  for (int r = 0; r < 4; ++r) {
    int j = grow + r;
    int kk = j & 31;
    hidx[r] = (4 + (j >> 5)) * 512 + ((kk >> 3) * 16 + bcol) * 8 + (kk & 7);
  }

  float c0 = 0.f, c1 = 0.f, c2 = 0.f, c3 = 0.f;
  float h0 = 0.f, h1 = 0.f, h2 = 0.f, h3 = 0.f;

  float xa = xp0[0], xb = xp1[0];   // t=0 prefetch (len >= 1 always)

  for (int t = 0; t < lmax; ++t) {
    xh[xd0] = f32_to_bf16(xa);
    xh[xd1] = f32_to_bf16(xb);
    __syncthreads();               // x_t staged AND h(t-1) visible

    // prefetch next step's x (HBM latency hidden under MFMA phase)
    if (t + 1 < lmax) { xa = xp0[(size_t)(t + 1) * NI]; xb = xp1[(size_t)(t + 1) * NI]; }

    f32x4 acc0 = bsf0, acc1 = bsf1, acc2 = bsf2, acc3 = bsf3;
    bf16x8 a0 = Ap0[0], a1 = Ap1[0], a2 = Ap2[0], a3 = Ap3[0];
#pragma unroll
    for (int kt = 0; kt < NKT; ++kt) {
      bf16x8 bf = *(const bf16x8*)&xh[kt * 512 + lane * 8];
      bf16x8 n0 = a0, n1 = a1, n2 = a2, n3 = a3;
      if (kt + 1 < NKT) {
        n0 = Ap0[(kt + 1) * 64]; n1 = Ap1[(kt + 1) * 64];
        n2 = Ap2[(kt + 1) * 64]; n3 = Ap3[(kt + 1) * 64];
      }
      acc0 = __builtin_amdgcn_mfma_f32_16x16x32_bf16(a0, bf, acc0, 0, 0, 0);
      acc1 = __builtin_amdgcn_mfma_f32_16x16x32_bf16(a1, bf, acc1, 0, 0, 0);
      acc2 = __builtin_amdgcn_mfma_f32_16x16x32_bf16(a2, bf, acc2, 0, 0, 0);
      acc3 = __builtin_amdgcn_mfma_f32_16x16x32_bf16(a3, bf, acc3, 0, 0, 0);
      a0 = n0; a1 = n1; a2 = n2; a3 = n3;
    }

    const bool upd = (t < lenb);   // per-lane freeze (packed-seq semantics)
#define CELL(r, cr, hr)                                                  \
    {                                                                    \
      float ig = 1.f / (1.f + __expf(-acc0[r]));                         \
      float fg = 1.f / (1.f + __expf(-acc1[r]));                         \
      float gg = 1.f - 2.f / (1.f + __expf(2.f * acc2[r]));              \
      float og = 1.f / (1.f + __expf(-acc3[r]));                         \
      float cn = fg * cr + ig * gg;                                      \
      float hn = og * (1.f - 2.f / (1.f + __expf(2.f * cn)));            \
      if (upd) { cr = cn; hr = hn; }                                     \
    }
    CELL(0, c0, h0) CELL(1, c1, h1) CELL(2, c2, h2) CELL(3, c3, h3)
#undef CELL

    __syncthreads();               // all B-frag reads done before overwrite
    if (upd) {
      xh[hidx[0]] = f32_to_bf16(h0);
      xh[hidx[1]] = f32_to_bf16(h1);
      xh[hidx[2]] = f32_to_bf16(h2);
      xh[hidx[3]] = f32_to_bf16(h3);
    }
  }

  // ---- LayerNorm: gather f32 h, wave w normalizes sequence w ----
  hf[bcol * 260 + grow + 0] = h0;
  hf[bcol * 260 + grow + 1] = h1;
  hf[bcol * 260 + grow + 2] = h2;
  hf[bcol * 260 + grow + 3] = h3;
  __syncthreads();

  float4 hv = *(const float4*)&hf[w * 260 + lane * 4];
  float s = hv.x + hv.y + hv.z + hv.w;
  float q = hv.x * hv.x + hv.y * hv.y + hv.z * hv.z + hv.w * hv.w;
#pragma unroll
  for (int off = 32; off > 0; off >>= 1) {
    s += __shfl_xor(s, off);
    q += __shfl_xor(q, off);
  }
  float mu = s * (1.f / NH);
  float rstd = rsqrtf(q * (1.f / NH) - mu * mu + EPSV);
  float4 g4 = *(const float4*)(gamma + lane * 4);
  float4 be4 = *(const float4*)(beta + lane * 4);
  float4 o;
  o.x = (hv.x - mu) * rstd * g4.x + be4.x;
  o.y = (hv.y - mu) * rstd * g4.y + be4.y;
  o.z = (hv.z - mu) * rstd * g4.z + be4.z;
  o.w = (hv.w - mu) * rstd * g4.w + be4.w;
  *(float4*)(out + (size_t)sseq[w] * NH + lane * 4) = o;
}

extern "C" void kernel_launch(void* const* d_in, const int* in_sizes, int n_in,
                              void* d_out, int out_size, void* d_ws, size_t ws_size,
                              hipStream_t stream) {
  const float* X       = (const float*)d_in[0];
  const int*   lengths = (const int*)d_in[1];
  const float* W_ih    = (const float*)d_in[2];
  const float* W_hh    = (const float*)d_in[3];
  const float* b_ih    = (const float*)d_in[4];
  const float* b_hh    = (const float*)d_in[5];
  const float* gamma   = (const float*)d_in[6];
  const float* beta    = (const float*)d_in[7];
  float* out = (float*)d_out;

  // workspace: Wsw 768 KB | bsum 4 KB | perm 2 KB
  unsigned short* Wsw = (unsigned short*)d_ws;
  float* bsum = (float*)((char*)d_ws + (size_t)64 * NKT * 512 * sizeof(unsigned short));
  int* perm = (int*)((char*)bsum + NG * sizeof(float));

  int total = 64 * NKT * 512;
  prep_kernel<<<(total + 255) / 256, 256, 0, stream>>>(W_ih, W_hh, b_ih, b_hh, Wsw, bsum);
  sort_kernel<<<1, NB, 0, stream>>>(lengths, perm);
  lstm_ln_kernel<<<NGRP, 1024, 0, stream>>>(X, lengths, perm, Wsw, bsum, gamma, beta, out);
}